// Round 1
// baseline (179.934 us; speedup 1.0000x reference)
//
#include <hip/hip_runtime.h>
#include <stdint.h>

// Problem constants (from reference)
#define N_NODES_C 100000
#define N_EDGES_C 600000
#define H_C 128

#define NTILES 3125            // N_NODES_C / 32
#define NB 512                 // grid: 2 blocks/CU guaranteed resident (barrier-safe)
#define TPB 512                // 8 waves per block
#define NQ 75000               // edge quarters (8 edges each)
#define QSTR 16384             // (NB*TPB)/16 quarters per grid sweep
#define LDS_STRIDE 136         // bf16 elems per LDS row: 128 + 8 pad

typedef __bf16 bf16x8 __attribute__((ext_vector_type(8)));
typedef float f32x16 __attribute__((ext_vector_type(16)));
typedef float f32x4v __attribute__((ext_vector_type(4)));
typedef _Float16 half8 __attribute__((ext_vector_type(8)));
typedef unsigned short ushort8 __attribute__((ext_vector_type(8)));

// fp32 -> bf16 round-to-nearest-even
__device__ __forceinline__ unsigned short f2bf(float f) {
    unsigned int u = __builtin_bit_cast(unsigned int, f);
    u += 0x7fffu + ((u >> 16) & 1u);
    return (unsigned short)(u >> 16);
}

__device__ __forceinline__ int agent_ld_relaxed(int* p) {
    return __hip_atomic_load(p, __ATOMIC_RELAXED, __HIP_MEMORY_SCOPE_AGENT);
}
__device__ __forceinline__ void agent_st_relaxed(int* p, int v) {
    __hip_atomic_store(p, v, __ATOMIC_RELAXED, __HIP_MEMORY_SCOPE_AGENT);
}

// Fused kernel:
//   Phase 1 (node GEMM): 8 waves/block, wave wv owns one 32-col N-subtile of
//     the 256-wide combined [u';v] output. B fragments primed ONCE per block
//     directly from W1 (fp32 -> bf16 in-reg). Grid-stride over 3125 32-node
//     tiles; next tile's z loads issued before the MFMA of the current tile.
//   Grid barrier: flag-array (one store per block, block 0 gathers, single
//     release flag). Flags memset to 0 by kernel_launch each iteration.
//     __threadfence() (agent scope) provides cross-XCD L2 wb/inv for uv.
//   Phase 2 (edges): identical math to the proven edge kernel, grid-strided.
__launch_bounds__(TPB, 4)
__global__ void fused_kernel(const float* __restrict__ z,
                             const int* __restrict__ ei,
                             const float* __restrict__ W1,
                             const float* __restrict__ b1,
                             const float* __restrict__ w2,
                             const float* __restrict__ b2,
                             float* __restrict__ out,
                             int* __restrict__ bar,
                             _Float16* __restrict__ uv) {
    __shared__ unsigned short smem[32 * LDS_STRIDE];   // 8704 B

    const int tid  = threadIdx.x;
    const int bid  = blockIdx.x;
    const int lane = tid & 63;
    const int wv   = tid >> 6;          // wave 0..7
    const int l31  = lane & 31;
    const int half = lane >> 5;
    const int uh   = wv >> 2;           // 0 = u half (adds b1), 1 = v half
    const int ncol = (wv & 3) * 32 + l31;   // column within the u/v half

    // ---- Phase 1: prime B fragments directly from W1 (once per block) ----
    // B[k][n2] fragment for 32x32x16: lane holds k = s*16 + half*8 + j,
    // n = ncol (within half); u half reads W1[k][n], v half W1[128+k][n].
    bf16x8 bfrag[8];
    {
        const float* wb = W1 + (size_t)(uh * H_C + half * 8) * H_C + ncol;
        #pragma unroll
        for (int s = 0; s < 8; ++s) {
            #pragma unroll
            for (int j = 0; j < 8; ++j) {
                unsigned short b = f2bf(wb[(s * 16 + j) * H_C]);
                bfrag[s][j] = __builtin_bit_cast(__bf16, b);
            }
        }
    }
    const float  badd    = uh ? 0.0f : b1[wv * 32 + l31];
    const size_t segbase = uh ? (size_t)N_NODES_C * H_C : (size_t)0;

    // Staging geometry: 512 threads cover a 32x128 fp32 tile, 8 floats each.
    const int sr = tid >> 4;          // row 0..31
    const int sc = (tid & 15) * 8;    // col 0,8,...,120

    int t = bid;                      // all bids < NB <= NTILES
    f32x4v fa, fb;
    {
        const float* src = z + (size_t)(t * 32 + sr) * H_C + sc;
        fa = *reinterpret_cast<const f32x4v*>(src);
        fb = *reinterpret_cast<const f32x4v*>(src + 4);
    }
    for (;;) {
        __syncthreads();              // smem free (prev tile's ds_reads done)
        {
            ushort8 u8;
            #pragma unroll
            for (int jj = 0; jj < 4; ++jj) {
                u8[jj]     = f2bf(fa[jj]);
                u8[jj + 4] = f2bf(fb[jj]);
            }
            *reinterpret_cast<ushort8*>(smem + sr * LDS_STRIDE + sc) = u8;
        }
        const int tn = t + NB;
        if (tn < NTILES) {            // prefetch next tile under MFMA+epilogue
            const float* src = z + (size_t)(tn * 32 + sr) * H_C + sc;
            fa = *reinterpret_cast<const f32x4v*>(src);
            fb = *reinterpret_cast<const f32x4v*>(src + 4);
        }
        __syncthreads();              // smem ready

        f32x16 acc = {};
        #pragma unroll
        for (int s = 0; s < 8; ++s) {
            bf16x8 a = *reinterpret_cast<const bf16x8*>(
                           smem + l31 * LDS_STRIDE + s * 16 + half * 8);
            acc = __builtin_amdgcn_mfma_f32_32x32x16_bf16(a, bfrag[s], acc, 0, 0, 0);
        }

        const int node0 = t * 32;
        #pragma unroll
        for (int r = 0; r < 16; ++r) {
            const int row = (r & 3) + 8 * (r >> 2) + 4 * half;  // C/D row map
            float v  = acc[r] + badd;
            float fo = __shfl_xor(v, 1);
            if ((lane & 1) == 0) {
                unsigned int pk = __builtin_bit_cast(
                    unsigned int, __builtin_amdgcn_cvt_pkrtz(v, fo));
                *reinterpret_cast<unsigned int*>(
                    uv + segbase + (size_t)(node0 + row) * H_C + ncol) = pk;
            }
        }
        if (tn >= NTILES) break;
        t = tn;
    }

    // ---- Grid barrier (uv ready). Flags pre-zeroed by host memset. ----
    __syncthreads();                  // all waves' uv stores issued (vmcnt drained)
    if (tid == 0) {
        __threadfence();              // agent-scope wb: uv dirty lines -> LLC
        agent_st_relaxed(&bar[bid], 1);
    }
    if (bid == 0) {
        for (int i = tid; i < NB; i += TPB)       // one flag per thread
            while (agent_ld_relaxed(&bar[i]) == 0) {}
        __syncthreads();                           // all 512 flags observed
        if (tid == 0) agent_st_relaxed(&bar[NB], 1);
    }
    if (tid == 0) {
        while (agent_ld_relaxed(&bar[NB]) == 0) {}
        __threadfence();              // agent-scope inv: drop stale L2 lines
    }
    __syncthreads();

    // ---- Phase 2: edge MLP. Quarter-wave (16 lanes) per 8 edges. ----
    const int ql = tid & 15;
    float w2v[8];
    {
        f32x4v a = *reinterpret_cast<const f32x4v*>(w2 + ql * 8);
        f32x4v b = *reinterpret_cast<const f32x4v*>(w2 + ql * 8 + 4);
        #pragma unroll
        for (int k = 0; k < 4; ++k) { w2v[k] = a[k]; w2v[k + 4] = b[k]; }
    }
    const float c2 = b2[0];
    const _Float16* __restrict__ vb = uv + (size_t)N_NODES_C * H_C;

    for (int q = (bid * TPB + tid) >> 4; q < NQ; q += QSTR) {
        const int e0 = q * 8;
        int4 sa = *reinterpret_cast<const int4*>(ei + e0);
        int4 sb = *reinterpret_cast<const int4*>(ei + e0 + 4);
        int4 da = *reinterpret_cast<const int4*>(ei + N_EDGES_C + e0);
        int4 db = *reinterpret_cast<const int4*>(ei + N_EDGES_C + e0 + 4);

        int se[8] = { sa.x, sa.y, sa.z, sa.w, sb.x, sb.y, sb.z, sb.w };
        int de[8] = { da.x, da.y, da.z, da.w, db.x, db.y, db.z, db.w };

        half8 uu[8], vv[8];
        #pragma unroll
        for (int i = 0; i < 8; ++i) {
            uu[i] = *reinterpret_cast<const half8*>(uv + (size_t)se[i] * H_C + ql * 8);
            vv[i] = *reinterpret_cast<const half8*>(vb + (size_t)de[i] * H_C + ql * 8);
        }

        float p[8];
        #pragma unroll
        for (int i = 0; i < 8; ++i) {
            float acc = 0.0f;
            #pragma unroll
            for (int k = 0; k < 8; ++k) {
                float h = (float)uu[i][k] + (float)vv[i][k];
                h = h > 0.0f ? h : 0.0f;
                acc = fmaf(h, w2v[k], acc);
            }
            p[i] = acc;
        }
        #pragma unroll
        for (int m = 1; m <= 8; m <<= 1) {
            #pragma unroll
            for (int i = 0; i < 8; ++i) p[i] += __shfl_xor(p[i], m);
        }
        if (ql == 0) {
            float4 o0 = { p[0] + c2, p[1] + c2, p[2] + c2, p[3] + c2 };
            float4 o1 = { p[4] + c2, p[5] + c2, p[6] + c2, p[7] + c2 };
            *reinterpret_cast<float4*>(out + e0)     = o0;
            *reinterpret_cast<float4*>(out + e0 + 4) = o1;
        }
    }
}

extern "C" void kernel_launch(void* const* d_in, const int* in_sizes, int n_in,
                              void* d_out, int out_size, void* d_ws, size_t ws_size,
                              hipStream_t stream) {
    const float* z  = (const float*)d_in[0];
    const int*   ei = (const int*)d_in[1];
    const float* W1 = (const float*)d_in[2];
    const float* b1 = (const float*)d_in[3];
    const float* W2 = (const float*)d_in[4];
    const float* b2 = (const float*)d_in[5];
    float* out = (float*)d_out;

    // Workspace: [barrier flags: 4 KB][uv: u' then v, 2*100000*128 fp16 = 51.2 MB]
    int* bar = (int*)d_ws;
    _Float16* uv = (_Float16*)((char*)d_ws + 4096);

    hipMemsetAsync(d_ws, 0, 4096, stream);   // reset barrier flags (capture-safe)
    fused_kernel<<<NB, TPB, 0, stream>>>(z, ei, W1, b1, W2, b2, out, bar, uv);
}

// Round 2
// 152.337 us; speedup vs baseline: 1.1812x; 1.1812x over previous
//
#include <hip/hip_runtime.h>
#include <hip/hip_bf16.h>
#include <stdint.h>

// Problem constants (from reference)
#define N_NODES_C 100000
#define N_EDGES_C 600000
#define H_C 128

// MFMA fragment types: 32x32x16 bf16 -> A/B = 8 bf16 (4 VGPR), C/D = 16 f32
typedef __bf16 bf16x8 __attribute__((ext_vector_type(8)));
typedef float f32x16 __attribute__((ext_vector_type(16)));
typedef float f32x4v __attribute__((ext_vector_type(4)));
typedef _Float16 half8 __attribute__((ext_vector_type(8)));
typedef unsigned short ushort8 __attribute__((ext_vector_type(8)));

#define LDS_STRIDE 136   // bf16 elems per LDS row: 128 + 8 pad (16-B aligned)

// fp32 -> bf16 round-to-nearest-even
__device__ __forceinline__ unsigned short f2bf(float f) {
    unsigned int u = __builtin_bit_cast(unsigned int, f);
    u += 0x7fffu + ((u >> 16) & 1u);
    return (unsigned short)(u >> 16);
}

// Kernel 1: W1 fp32 [256,128] -> bf16 combined-B in MFMA B-fragment order.
// Bc[k][n2], k=0..127, n2=0..255:  n2<128 -> W1[k][n2] (u path),
//                                  n2>=128 -> W1[128+k][n2-128] (v path).
// Fragment (s = K-step 0..7, T = N-subtile 0..7): lane L holds
// Bc[k = s*16 + (L>>5)*8 + j][n2 = T*32 + (L&31)], j = 0..7 contiguous.
// Flat index: ((s*8 + T)*64 + L)*8 + j   (32768 elements, 64 KB)
__global__ void w1fmt_kernel(const float* __restrict__ W1,
                             unsigned short* __restrict__ w1f) {
    int i = blockIdx.x * blockDim.x + threadIdx.x;
    if (i >= 8 * 8 * 64 * 8) return;
    int j = i & 7;
    int L = (i >> 3) & 63;
    int t = (i >> 9) & 7;
    int s = (i >> 12) & 7;
    int k  = s * 16 + ((L >> 5) * 8) + j;   // 0..127
    int n2 = t * 32 + (L & 31);             // 0..255
    float w = (n2 < 128) ? W1[k * H_C + n2]
                         : W1[(128 + k) * H_C + (n2 - 128)];
    w1f[i] = f2bf(w);
}

// Kernel 2 (v3, proven): node GEMM with LDS-staged A.
//  uv[0:N*128)  = u' = z @ W1[:128] + b1 (fp16)
//  uv[N*128: )  = v  = z @ W1[128:]      (fp16)
// One block = one 32-node tile. 256 threads coalesced-load the 16-KB z chunk
// (16 contiguous floats each), convert to bf16 once, stage in LDS (stride
// 136). Wave wv owns N-subtiles {2wv, 2wv+1}; B-fragments register-primed
// from w1f. MFMA loop is pure ds_read_b128 + MFMA.
__launch_bounds__(256, 2)
__global__ void node_gemm_kernel(const float* __restrict__ z,
                                 const unsigned short* __restrict__ w1f,
                                 const float* __restrict__ b1,
                                 _Float16* __restrict__ uv) {
    __shared__ unsigned short smem[32 * LDS_STRIDE];   // 8704 B

    const int lane = threadIdx.x & 63;
    const int wv   = threadIdx.x >> 6;      // wave 0..3
    const int l31  = lane & 31;
    const int half = lane >> 5;
    const int uh   = wv >> 1;               // 0 = u half (b1), 1 = v half
    const int tile = blockIdx.x;            // 32-node tile, one per block

    // ---- Stage A: coalesced global read -> bf16 -> LDS ----
    {
        const int sr = threadIdx.x >> 3;          // row 0..31
        const int sc = (threadIdx.x & 7) * 16;    // col 0,16,...,112
        const float* src = z + (size_t)(tile * 32 + sr) * H_C + sc;
        f32x4v f0 = *reinterpret_cast<const f32x4v*>(src);
        f32x4v f1 = *reinterpret_cast<const f32x4v*>(src + 4);
        f32x4v f2 = *reinterpret_cast<const f32x4v*>(src + 8);
        f32x4v f3 = *reinterpret_cast<const f32x4v*>(src + 12);
        ushort8 lo, hi;
        #pragma unroll
        for (int j = 0; j < 4; ++j) {
            lo[j]     = f2bf(f0[j]);
            lo[j + 4] = f2bf(f1[j]);
            hi[j]     = f2bf(f2[j]);
            hi[j + 4] = f2bf(f3[j]);
        }
        *reinterpret_cast<ushort8*>(smem + sr * LDS_STRIDE + sc)     = lo;
        *reinterpret_cast<ushort8*>(smem + sr * LDS_STRIDE + sc + 8) = hi;
    }

    // ---- Prime B fragments from w1f (coalesced, L2-hot) ----
    bf16x8 bfrag[8][2];
    #pragma unroll
    for (int s = 0; s < 8; ++s) {
        #pragma unroll
        for (int t = 0; t < 2; ++t) {
            bfrag[s][t] = reinterpret_cast<const bf16x8*>(w1f)
                              [(s * 8 + wv * 2 + t) * 64 + lane];
        }
    }

    float badd[2];
    int   ncol[2];
    #pragma unroll
    for (int t = 0; t < 2; ++t) {
        int n2  = (wv * 2 + t) * 32 + l31;  // global column 0..255
        ncol[t] = n2 - uh * 128;            // column within u/v half
        badd[t] = uh ? 0.0f : b1[n2];
    }
    const size_t segbase = uh ? (size_t)N_NODES_C * H_C : 0;

    __syncthreads();

    // ---- MFMA loop: A from LDS (m = l31, k = s*16 + half*8 + j) ----
    f32x16 acc[2] = {};
    #pragma unroll
    for (int s = 0; s < 8; ++s) {
        bf16x8 a = *reinterpret_cast<const bf16x8*>(
                       smem + l31 * LDS_STRIDE + s * 16 + half * 8);
        acc[0] = __builtin_amdgcn_mfma_f32_32x32x16_bf16(a, bfrag[s][0], acc[0], 0, 0, 0);
        acc[1] = __builtin_amdgcn_mfma_f32_32x32x16_bf16(a, bfrag[s][1], acc[1], 0, 0, 0);
    }

    // ---- Epilogue: +b1 (u half), fp16 pack via lane-pair shuffle, store ----
    const int node0 = tile * 32;
    #pragma unroll
    for (int t = 0; t < 2; ++t) {
        #pragma unroll
        for (int r = 0; r < 16; ++r) {
            int row = (r & 3) + 8 * (r >> 2) + 4 * half;    // C/D row map
            float v = acc[t][r] + badd[t];
            float fo = __shfl_xor(v, 1);
            if ((lane & 1) == 0) {
                unsigned int pk = __builtin_bit_cast(
                    unsigned int, __builtin_amdgcn_cvt_pkrtz(v, fo));
                size_t idx = segbase + (size_t)(node0 + row) * H_C + ncol[t];
                *reinterpret_cast<unsigned int*>(uv + idx) = pk;
            }
        }
    }
}

// Kernel 3 (v2): edge phase. Quarter-wave (16 lanes) per SIXTEEN consecutive
// edges. Round-0 version used 8 edges/quarter but the compiler's 48-VGPR
// allocation serialized the 16 gathers into ~6-8 outstanding. Here: 32
// row-gathers (16 B/lane each) issued before any consumption, ~190 VGPR,
// __launch_bounds__(256,2) caps at 256 VGPR (2 waves/SIMD, 8 waves/CU) --
// trading occupancy for per-wave MLP on the latency-bound gather pipe.
__launch_bounds__(256, 2)
__global__ void edge_kernel(const _Float16* __restrict__ uv,
                            const int* __restrict__ ei,
                            const float* __restrict__ w2,
                            const float* __restrict__ b2,
                            float* __restrict__ out) {
    const int tid = blockIdx.x * blockDim.x + threadIdx.x;
    const int j   = tid & 15;                       // lane within quarter
    const int q   = tid >> 4;                       // quarter id
    const int e0  = q * 16;
    if (e0 >= N_EDGES_C) return;

    float w2v[8];
    {
        f32x4v a = *reinterpret_cast<const f32x4v*>(w2 + j * 8);
        f32x4v b = *reinterpret_cast<const f32x4v*>(w2 + j * 8 + 4);
        #pragma unroll
        for (int k = 0; k < 4; ++k) { w2v[k] = a[k]; w2v[k + 4] = b[k]; }
    }
    const float c2 = b2[0];
    const _Float16* __restrict__ vbase = uv + (size_t)N_NODES_C * H_C;

    int se[16], de[16];
    #pragma unroll
    for (int g = 0; g < 4; ++g) {
        int4 s4 = *reinterpret_cast<const int4*>(ei + e0 + 4 * g);
        int4 d4 = *reinterpret_cast<const int4*>(ei + N_EDGES_C + e0 + 4 * g);
        se[4 * g + 0] = s4.x; se[4 * g + 1] = s4.y;
        se[4 * g + 2] = s4.z; se[4 * g + 3] = s4.w;
        de[4 * g + 0] = d4.x; de[4 * g + 1] = d4.y;
        de[4 * g + 2] = d4.z; de[4 * g + 3] = d4.w;
    }

    // 32 independent 16-B gathers, all issued before first use
    half8 uu[16], vv[16];
    #pragma unroll
    for (int i = 0; i < 16; ++i) {
        uu[i] = *reinterpret_cast<const half8*>(uv    + (size_t)se[i] * H_C + j * 8);
        vv[i] = *reinterpret_cast<const half8*>(vbase + (size_t)de[i] * H_C + j * 8);
    }

    float p[16];
    #pragma unroll
    for (int i = 0; i < 16; ++i) {
        float acc = 0.0f;
        #pragma unroll
        for (int k = 0; k < 8; ++k) {
            float h = (float)uu[i][k] + (float)vv[i][k];
            h = h > 0.0f ? h : 0.0f;
            acc = fmaf(h, w2v[k], acc);
        }
        p[i] = acc;
    }
    #pragma unroll
    for (int m = 1; m <= 8; m <<= 1) {
        #pragma unroll
        for (int i = 0; i < 16; ++i) p[i] += __shfl_xor(p[i], m);
    }
    if (j == 0) {
        #pragma unroll
        for (int g = 0; g < 4; ++g) {
            float4 o = { p[4 * g + 0] + c2, p[4 * g + 1] + c2,
                         p[4 * g + 2] + c2, p[4 * g + 3] + c2 };
            *reinterpret_cast<float4*>(out + e0 + 4 * g) = o;
        }
    }
}

extern "C" void kernel_launch(void* const* d_in, const int* in_sizes, int n_in,
                              void* d_out, int out_size, void* d_ws, size_t ws_size,
                              hipStream_t stream) {
    const float* z  = (const float*)d_in[0];
    const int*   ei = (const int*)d_in[1];
    const float* W1 = (const float*)d_in[2];
    const float* b1 = (const float*)d_in[3];
    const float* W2 = (const float*)d_in[4];
    const float* b2 = (const float*)d_in[5];
    float* out = (float*)d_out;

    // Workspace: [w1f: 64 KB][uv: u' then v, 2 * 100000*128 fp16 = 51.2 MB]
    unsigned short* w1f = (unsigned short*)d_ws;
    _Float16* uv = (_Float16*)((char*)d_ws + 65536);

    w1fmt_kernel<<<(8 * 8 * 64 * 8 + 255) / 256, 256, 0, stream>>>(W1, w1f);

    node_gemm_kernel<<<N_NODES_C / 32, 256, 0, stream>>>(z, w1f, b1, uv);

    // 16 edges per quarter-wave: 600000/16 = 37500 quarters = 600000 threads
    edge_kernel<<<(N_EDGES_C + 255) / 256, 256, 0, stream>>>(uv, ei, W2, b2, out);
}

// Round 3
// 151.521 us; speedup vs baseline: 1.1875x; 1.0054x over previous
//
#include <hip/hip_runtime.h>
#include <hip/hip_bf16.h>
#include <stdint.h>

// Problem constants (from reference)
#define N_NODES_C 100000
#define N_EDGES_C 600000
#define H_C 128

#define NTILES 3125      // 32-node tiles

// MFMA fragment types: 32x32x16 bf16 -> A/B = 8 bf16 (4 VGPR), C/D = 16 f32
typedef __bf16 bf16x8 __attribute__((ext_vector_type(8)));
typedef float f32x16 __attribute__((ext_vector_type(16)));
typedef float f32x4v __attribute__((ext_vector_type(4)));
typedef _Float16 half8 __attribute__((ext_vector_type(8)));
typedef unsigned short ushort8 __attribute__((ext_vector_type(8)));

#define LDS_STRIDE 136   // bf16 elems per LDS row: 128 + 8 pad (16-B aligned)

// fp32 -> bf16 round-to-nearest-even
__device__ __forceinline__ unsigned short f2bf(float f) {
    unsigned int u = __builtin_bit_cast(unsigned int, f);
    u += 0x7fffu + ((u >> 16) & 1u);
    return (unsigned short)(u >> 16);
}

// Kernel 1: W1 fp32 [256,128] -> bf16 combined-B in MFMA B-fragment order.
// Bc[k][n2], k=0..127, n2=0..255:  n2<128 -> W1[k][n2] (u path),
//                                  n2>=128 -> W1[128+k][n2-128] (v path).
// Fragment (s = K-step 0..7, T = N-subtile 0..7): lane L holds
// Bc[k = s*16 + (L>>5)*8 + j][n2 = T*32 + (L&31)], j = 0..7 contiguous.
// Flat index: ((s*8 + T)*64 + L)*8 + j   (32768 elements, 64 KB)
__global__ void w1fmt_kernel(const float* __restrict__ W1,
                             unsigned short* __restrict__ w1f) {
    int i = blockIdx.x * blockDim.x + threadIdx.x;
    if (i >= 8 * 8 * 64 * 8) return;
    int j = i & 7;
    int L = (i >> 3) & 63;
    int t = (i >> 9) & 7;
    int s = (i >> 12) & 7;
    int k  = s * 16 + ((L >> 5) * 8) + j;   // 0..127
    int n2 = t * 32 + (L & 31);             // 0..255
    float w = (n2 < 128) ? W1[k * H_C + n2]
                         : W1[(128 + k) * H_C + (n2 - 128)];
    w1f[i] = f2bf(w);
}

// Kernel 2 (v4): node GEMM, TWO 32-node tiles per block, software-pipelined.
//  uv[0:N*128)  = u' = z @ W1[:128] + b1 (fp16)
//  uv[N*128: )  = v  = z @ W1[128:]      (fp16)
// Tile t1's 16-KB z load is issued before the first barrier and completes
// under tile t0's MFMA + epilogue (double-buffered LDS). B-fragment priming
// (L2-hot w1f reads) amortized over both tiles. Math order per tile is
// identical to the proven v3 kernel.
__launch_bounds__(256, 2)
__global__ void node_gemm_kernel(const float* __restrict__ z,
                                 const unsigned short* __restrict__ w1f,
                                 const float* __restrict__ b1,
                                 _Float16* __restrict__ uv) {
    __shared__ unsigned short smem[2][32 * LDS_STRIDE];   // 17408 B

    const int lane = threadIdx.x & 63;
    const int wv   = threadIdx.x >> 6;      // wave 0..3
    const int l31  = lane & 31;
    const int half = lane >> 5;
    const int uh   = wv >> 1;               // 0 = u half (b1), 1 = v half
    const int t0   = blockIdx.x * 2;
    const int t1   = t0 + 1;                // may be == NTILES (odd count)

    const int sr = threadIdx.x >> 3;          // staging row 0..31
    const int sc = (threadIdx.x & 7) * 16;    // staging col 0,16,...,112

    // ---- Issue tile-0 z load (HBM) ----
    const float* src0 = z + (size_t)(t0 * 32 + sr) * H_C + sc;
    f32x4v f0 = *reinterpret_cast<const f32x4v*>(src0);
    f32x4v f1 = *reinterpret_cast<const f32x4v*>(src0 + 4);
    f32x4v f2 = *reinterpret_cast<const f32x4v*>(src0 + 8);
    f32x4v f3 = *reinterpret_cast<const f32x4v*>(src0 + 12);

    // ---- Prime B fragments from w1f (coalesced, L2-hot) ----
    bf16x8 bfrag[8][2];
    #pragma unroll
    for (int s = 0; s < 8; ++s) {
        #pragma unroll
        for (int t = 0; t < 2; ++t) {
            bfrag[s][t] = reinterpret_cast<const bf16x8*>(w1f)
                              [(s * 8 + wv * 2 + t) * 64 + lane];
        }
    }

    float badd[2];
    int   ncol[2];
    #pragma unroll
    for (int t = 0; t < 2; ++t) {
        int n2  = (wv * 2 + t) * 32 + l31;  // global column 0..255
        ncol[t] = n2 - uh * 128;            // column within u/v half
        badd[t] = uh ? 0.0f : b1[n2];
    }
    const size_t segbase = uh ? (size_t)N_NODES_C * H_C : 0;

    // ---- cvt tile-0 -> LDS buffer 0 ----
    {
        ushort8 lo, hi;
        #pragma unroll
        for (int j = 0; j < 4; ++j) {
            lo[j]     = f2bf(f0[j]);
            lo[j + 4] = f2bf(f1[j]);
            hi[j]     = f2bf(f2[j]);
            hi[j + 4] = f2bf(f3[j]);
        }
        *reinterpret_cast<ushort8*>(smem[0] + sr * LDS_STRIDE + sc)     = lo;
        *reinterpret_cast<ushort8*>(smem[0] + sr * LDS_STRIDE + sc + 8) = hi;
    }

    // ---- Prefetch tile-1 z into registers (in flight during t0 compute) ----
    f32x4v g0, g1, g2, g3;
    if (t1 < NTILES) {
        const float* src1 = z + (size_t)(t1 * 32 + sr) * H_C + sc;
        g0 = *reinterpret_cast<const f32x4v*>(src1);
        g1 = *reinterpret_cast<const f32x4v*>(src1 + 4);
        g2 = *reinterpret_cast<const f32x4v*>(src1 + 8);
        g3 = *reinterpret_cast<const f32x4v*>(src1 + 12);
    }

    __syncthreads();

    // ---- Tile 0: MFMA loop (A from LDS0) + epilogue ----
    {
        f32x16 acc[2] = {};
        #pragma unroll
        for (int s = 0; s < 8; ++s) {
            bf16x8 a = *reinterpret_cast<const bf16x8*>(
                           smem[0] + l31 * LDS_STRIDE + s * 16 + half * 8);
            acc[0] = __builtin_amdgcn_mfma_f32_32x32x16_bf16(a, bfrag[s][0], acc[0], 0, 0, 0);
            acc[1] = __builtin_amdgcn_mfma_f32_32x32x16_bf16(a, bfrag[s][1], acc[1], 0, 0, 0);
        }
        const int node0 = t0 * 32;
        #pragma unroll
        for (int t = 0; t < 2; ++t) {
            #pragma unroll
            for (int r = 0; r < 16; ++r) {
                int row = (r & 3) + 8 * (r >> 2) + 4 * half;    // C/D row map
                float v = acc[t][r] + badd[t];
                float fo = __shfl_xor(v, 1);
                if ((lane & 1) == 0) {
                    unsigned int pk = __builtin_bit_cast(
                        unsigned int, __builtin_amdgcn_cvt_pkrtz(v, fo));
                    size_t idx = segbase + (size_t)(node0 + row) * H_C + ncol[t];
                    *reinterpret_cast<unsigned int*>(uv + idx) = pk;
                }
            }
        }
    }

    // ---- cvt tile-1 -> LDS buffer 1 (no WAR hazard: separate buffer) ----
    if (t1 < NTILES) {
        ushort8 lo, hi;
        #pragma unroll
        for (int j = 0; j < 4; ++j) {
            lo[j]     = f2bf(g0[j]);
            lo[j + 4] = f2bf(g1[j]);
            hi[j]     = f2bf(g2[j]);
            hi[j + 4] = f2bf(g3[j]);
        }
        *reinterpret_cast<ushort8*>(smem[1] + sr * LDS_STRIDE + sc)     = lo;
        *reinterpret_cast<ushort8*>(smem[1] + sr * LDS_STRIDE + sc + 8) = hi;
    }

    __syncthreads();

    // ---- Tile 1: MFMA loop (A from LDS1) + epilogue ----
    if (t1 < NTILES) {
        f32x16 acc[2] = {};
        #pragma unroll
        for (int s = 0; s < 8; ++s) {
            bf16x8 a = *reinterpret_cast<const bf16x8*>(
                           smem[1] + l31 * LDS_STRIDE + s * 16 + half * 8);
            acc[0] = __builtin_amdgcn_mfma_f32_32x32x16_bf16(a, bfrag[s][0], acc[0], 0, 0, 0);
            acc[1] = __builtin_amdgcn_mfma_f32_32x32x16_bf16(a, bfrag[s][1], acc[1], 0, 0, 0);
        }
        const int node0 = t1 * 32;
        #pragma unroll
        for (int t = 0; t < 2; ++t) {
            #pragma unroll
            for (int r = 0; r < 16; ++r) {
                int row = (r & 3) + 8 * (r >> 2) + 4 * half;
                float v = acc[t][r] + badd[t];
                float fo = __shfl_xor(v, 1);
                if ((lane & 1) == 0) {
                    unsigned int pk = __builtin_bit_cast(
                        unsigned int, __builtin_amdgcn_cvt_pkrtz(v, fo));
                    size_t idx = segbase + (size_t)(node0 + row) * H_C + ncol[t];
                    *reinterpret_cast<unsigned int*>(uv + idx) = pk;
                }
            }
        }
    }
}

// Kernel 3 (round-0 proven form): edge phase. Quarter-wave (16 lanes) per
// EIGHT consecutive edges; 16 row-gathers in flight; per-edge dot with W2
// slice; xor-shuffle reduce; lane 0 stores two float4s.
// NOTE (r2 evidence): this phase is throughput-bound on L2-miss fabric
// traffic (~3.2 TB/s, FETCH ~141 MB structural). Deeper MLP (16 edges/
// quarter, 88 VGPR) did NOT help (45.5 vs 44.5 us) -- do not revisit.
__global__ void edge_kernel(const _Float16* __restrict__ uv,
                            const int* __restrict__ ei,
                            const float* __restrict__ w2,
                            const float* __restrict__ b2,
                            float* __restrict__ out) {
    const int tid = blockIdx.x * blockDim.x + threadIdx.x;
    const int j   = tid & 15;                       // lane within quarter
    const int q   = tid >> 4;                       // quarter id
    const int e0  = q * 8;
    if (e0 >= N_EDGES_C) return;

    float w2v[8];
    {
        f32x4v a = *reinterpret_cast<const f32x4v*>(w2 + j * 8);
        f32x4v b = *reinterpret_cast<const f32x4v*>(w2 + j * 8 + 4);
        #pragma unroll
        for (int k = 0; k < 4; ++k) { w2v[k] = a[k]; w2v[k + 4] = b[k]; }
    }
    const float c2 = b2[0];
    const _Float16* vbase = uv + (size_t)N_NODES_C * H_C;

    int4 sa = *reinterpret_cast<const int4*>(ei + e0);
    int4 sb = *reinterpret_cast<const int4*>(ei + e0 + 4);
    int4 da = *reinterpret_cast<const int4*>(ei + N_EDGES_C + e0);
    int4 db = *reinterpret_cast<const int4*>(ei + N_EDGES_C + e0 + 4);

    int se[8] = { sa.x, sa.y, sa.z, sa.w, sb.x, sb.y, sb.z, sb.w };
    int de[8] = { da.x, da.y, da.z, da.w, db.x, db.y, db.z, db.w };

    half8 uu[8], vv[8];
    #pragma unroll
    for (int i = 0; i < 8; ++i) {
        uu[i] = *reinterpret_cast<const half8*>(uv    + (size_t)se[i] * H_C + j * 8);
        vv[i] = *reinterpret_cast<const half8*>(vbase + (size_t)de[i] * H_C + j * 8);
    }

    float p[8];
    #pragma unroll
    for (int i = 0; i < 8; ++i) {
        float acc = 0.0f;
        #pragma unroll
        for (int k = 0; k < 8; ++k) {
            float h = (float)uu[i][k] + (float)vv[i][k];
            h = h > 0.0f ? h : 0.0f;
            acc = fmaf(h, w2v[k], acc);
        }
        p[i] = acc;
    }
    #pragma unroll
    for (int m = 1; m <= 8; m <<= 1) {
        #pragma unroll
        for (int i = 0; i < 8; ++i) p[i] += __shfl_xor(p[i], m);
    }
    if (j == 0) {
        float4 o0 = { p[0] + c2, p[1] + c2, p[2] + c2, p[3] + c2 };
        float4 o1 = { p[4] + c2, p[5] + c2, p[6] + c2, p[7] + c2 };
        *reinterpret_cast<float4*>(out + e0)     = o0;
        *reinterpret_cast<float4*>(out + e0 + 4) = o1;
    }
}

extern "C" void kernel_launch(void* const* d_in, const int* in_sizes, int n_in,
                              void* d_out, int out_size, void* d_ws, size_t ws_size,
                              hipStream_t stream) {
    const float* z  = (const float*)d_in[0];
    const int*   ei = (const int*)d_in[1];
    const float* W1 = (const float*)d_in[2];
    const float* b1 = (const float*)d_in[3];
    const float* W2 = (const float*)d_in[4];
    const float* b2 = (const float*)d_in[5];
    float* out = (float*)d_out;

    // Workspace: [w1f: 64 KB][uv: u' then v, 2 * 100000*128 fp16 = 51.2 MB]
    unsigned short* w1f = (unsigned short*)d_ws;
    _Float16* uv = (_Float16*)((char*)d_ws + 65536);

    w1fmt_kernel<<<(8 * 8 * 64 * 8 + 255) / 256, 256, 0, stream>>>(W1, w1f);

    // 2 tiles per block, NTILES = 3125 (odd) -> 1563 blocks, last does 1 tile
    node_gemm_kernel<<<(NTILES + 1) / 2, 256, 0, stream>>>(z, w1f, b1, uv);

    int nquarters = N_EDGES_C / 8;       // 75000
    edge_kernel<<<(nquarters * 16 + 255) / 256, 256, 0, stream>>>(uv, ei, W2, b2, out);
}